// Round 4
// baseline (146.687 us; speedup 1.0000x reference)
//
#include <hip/hip_runtime.h>
#include <math.h>

#define FCLAMP 10000.0f
#define NCYC 1024
#define NB2 (NCYC / 4)   // blocks in k_attn_final

__device__ __forceinline__ float safef(float x) {
    if (isnan(x)) return 0.0f;
    return fmaxf(fminf(x, FCLAMP), -FCLAMP);
}

// Butterfly reductions: every lane ends with the full-wave result.
__device__ __forceinline__ float wsum_b(float v) {
#pragma unroll
    for (int m = 1; m <= 32; m <<= 1) v += __shfl_xor(v, m, 64);
    return v;
}
__device__ __forceinline__ float wmax_b(float v) {
#pragma unroll
    for (int m = 1; m <= 32; m <<= 1) v = fmaxf(v, __shfl_xor(v, m, 64));
    return v;
}

// ---------------------------------------------------------------------------
// Kernel 1: ONE WAVE per cycle, 4 darts per lane. Zero barriers, zero LDS.
// Orientation scan via shuffles, 3-neighbor cycle attention via 2 lane-shfls,
// in-lane LN, redundant-per-lane cycle MLP, lane-parallel global QKV.
// ---------------------------------------------------------------------------
__global__ __launch_bounds__(64, 1) void k_cycle(
    const float* __restrict__ df,
    const float* __restrict__ de_w, const float* __restrict__ de_b,
    const float* __restrict__ ca_in_w, const float* __restrict__ ca_in_b,
    const float* __restrict__ ca_out_w, const float* __restrict__ ca_out_b,
    const float* __restrict__ cn_g, const float* __restrict__ cn_b,
    const float* __restrict__ cs_w, const float* __restrict__ cs_b,
    const float* __restrict__ cp_ln_g, const float* __restrict__ cp_ln_b,
    const float* __restrict__ cp_w1, const float* __restrict__ cp_b1,
    const float* __restrict__ cp_w2, const float* __restrict__ cp_b2,
    const float* __restrict__ ia_in_w, const float* __restrict__ ia_in_b,
    float* __restrict__ ws_cyc,   // [NCYC][8]
    float* __restrict__ ws_q,     // [NCYC][8]
    float* __restrict__ ws_kT,    // [8][NCYC]
    float* __restrict__ ws_vT,    // [8][NCYC]
    unsigned* __restrict__ ws_cnt)
{
    const int lane = threadIdx.x;
    const int nc   = blockIdx.x;
    if (nc == 0 && lane == 0) *ws_cnt = 0u;   // arm the attn/final fusion counter

    // 4 darts per lane, contiguous: darts (4*lane .. 4*lane+3), 12 floats.
    const float* base = df + (size_t)nc * 768 + lane * 12;
    const float4 A = *(const float4*)(base);
    const float4 B = *(const float4*)(base + 4);
    const float4 C = *(const float4*)(base + 8);
    float dxr[4] = {A.x, A.w, B.z, C.y};
    float dyr[4] = {A.y, B.x, B.w, C.z};

    // in-lane prefix, then exclusive wave scan of lane totals
    float sx[4], sy[4];
    sx[0] = dxr[0]; sy[0] = dyr[0];
#pragma unroll
    for (int r = 1; r < 4; ++r) { sx[r] = sx[r - 1] + dxr[r]; sy[r] = sy[r - 1] + dyr[r]; }
    const float tx = sx[3], ty = sy[3];
    float ixs = tx, iys = ty;
#pragma unroll
    for (int off = 1; off < 64; off <<= 1) {
        const float ax = __shfl_up(ixs, off, 64);
        const float ay = __shfl_up(iys, off, 64);
        if (lane >= off) { ixs += ax; iys += ay; }
    }
    const float bx = ixs - tx, by = iys - ty;   // sum of darts before this lane

    // shoelace: area*2 = sum_{i<255} cross(v_i, d_i)
    float cc = 0.f;
#pragma unroll
    for (int r = 0; r < 4; ++r) {
        const float vx = bx + (r ? sx[r - 1] : 0.f);
        const float vy = by + (r ? sy[r - 1] : 0.f);
        if ((lane * 4 + r) < 255) cc += vx * dyr[r] - vy * dxr[r];
    }
    const float area2 = wsum_b(cc);

    if (!(area2 >= 0.f)) {   // wave-uniform flip: new[j] = -old[255-j]
        float nx[4], ny[4];
#pragma unroll
        for (int r = 0; r < 4; ++r) {
            nx[r] = -__shfl(dxr[3 - r], 63 - lane, 64);
            ny[r] = -__shfl(dyr[3 - r], 63 - lane, 64);
        }
#pragma unroll
        for (int r = 0; r < 4; ++r) { dxr[r] = nx[r]; dyr[r] = ny[r]; }
    }

    // embed
    float embA[4][8];
#pragma unroll
    for (int r = 0; r < 4; ++r) {
        const float fx = safef(dxr[r]);
        const float fy = safef(dyr[r]);
        const float fn = safef(sqrtf(dxr[r] * dxr[r] + dyr[r] * dyr[r]));
#pragma unroll
        for (int j = 0; j < 8; ++j) {
            const float e = de_b[j] + fx * de_w[j * 3] + fy * de_w[j * 3 + 1] + fn * de_w[j * 3 + 2];
            embA[r][j] = safef(fmaxf(e, 0.f));
        }
    }

    // qkv (weights wave-uniform -> SGPR broadcast)
    float qA[4][8], kA[4][8], vA[4][8];
#pragma unroll
    for (int r = 0; r < 4; ++r) {
#pragma unroll
        for (int o = 0; o < 24; ++o) {
            float val = ca_in_b[o];
#pragma unroll
            for (int k = 0; k < 8; ++k) val += embA[r][k] * ca_in_w[o * 8 + k];
            if (o < 8)       qA[r][o] = val;
            else if (o < 16) kA[r][o - 8] = val;
            else             vA[r][o - 16] = val;
        }
    }

    // neighbor k/v across lanes (circular)
    const int lprev = (lane + 63) & 63, lnext = (lane + 1) & 63;
    float kp[8], kn[8], vp[8], vn[8];
#pragma unroll
    for (int d = 0; d < 8; ++d) {
        kp[d] = __shfl(kA[3][d], lprev, 64);
        kn[d] = __shfl(kA[0][d], lnext, 64);
        vp[d] = __shfl(vA[3][d], lprev, 64);
        vn[d] = __shfl(vA[0][d], lnext, 64);
    }

    // 3-neighbor attention + out-proj + residual + LN + logit, all in-lane
    float lgr[4];
#pragma unroll
    for (int r = 0; r < 4; ++r) {
        float kprev[8], knext[8], vprev[8], vnext[8];
#pragma unroll
        for (int d = 0; d < 8; ++d) {
            kprev[d] = (r == 0) ? kp[d] : kA[r - 1][d];
            knext[d] = (r == 3) ? kn[d] : kA[r + 1][d];
            vprev[d] = (r == 0) ? vp[d] : vA[r - 1][d];
            vnext[d] = (r == 3) ? vn[d] : vA[r + 1][d];
        }
        float att[8];
#pragma unroll
        for (int h = 0; h < 2; ++h) {
            float s0 = 0.f, s1 = 0.f, s2 = 0.f;
#pragma unroll
            for (int d = 0; d < 4; ++d) {
                const float qv = qA[r][h * 4 + d];
                s0 += qv * kprev[h * 4 + d];
                s1 += qv * kA[r][h * 4 + d];
                s2 += qv * knext[h * 4 + d];
            }
            s0 *= 0.5f; s1 *= 0.5f; s2 *= 0.5f;
            const float m  = fmaxf(s0, fmaxf(s1, s2));
            const float e0 = __expf(s0 - m), e1 = __expf(s1 - m), e2 = __expf(s2 - m);
            const float inv = 1.f / (e0 + e1 + e2);
#pragma unroll
            for (int d = 0; d < 4; ++d)
                att[h * 4 + d] = (e0 * vprev[h * 4 + d] + e1 * vA[r][h * 4 + d] +
                                  e2 * vnext[h * 4 + d]) * inv;
        }
        float x8[8];
#pragma unroll
        for (int j = 0; j < 8; ++j) {
            float ao = ca_out_b[j];
#pragma unroll
            for (int k = 0; k < 8; ++k) ao += att[k] * ca_out_w[j * 8 + k];
            x8[j] = safef(embA[r][j] + ao);
        }
        float mu = 0.f;
#pragma unroll
        for (int j = 0; j < 8; ++j) mu += x8[j];
        mu *= 0.125f;
        float var = 0.f;
#pragma unroll
        for (int j = 0; j < 8; ++j) { const float d = x8[j] - mu; var += d * d; }
        var *= 0.125f;
        const float rs = rsqrtf(var + 1e-5f);
        float lg = cs_b[0];
#pragma unroll
        for (int j = 0; j < 8; ++j) {
            embA[r][j] = safef((x8[j] - mu) * rs * cn_g[j] + cn_b[j]);  // emb2 overwrites embA
            lg += embA[r][j] * cs_w[j];
        }
        lgr[r] = safef(lg);
    }

    // dart softmax over 256 + weighted pool
    float M = fmaxf(fmaxf(lgr[0], lgr[1]), fmaxf(lgr[2], lgr[3]));
    M = wmax_b(M);
    float er[4], esum = 0.f;
#pragma unroll
    for (int r = 0; r < 4; ++r) { er[r] = __expf(lgr[r] - M); esum += er[r]; }
    const float S = wsum_b(esum);
    const float invS = 1.f / S;
    float pool[8];
#pragma unroll
    for (int j = 0; j < 8; ++j) {
        float pj = er[0] * embA[0][j] + er[1] * embA[1][j] + er[2] * embA[2][j] + er[3] * embA[3][j];
        pool[j] = wsum_b(pj) * invS;
    }

    // LN + cycle MLP, redundantly in every lane (all state in regs)
    float mu2 = 0.f;
#pragma unroll
    for (int j = 0; j < 8; ++j) mu2 += pool[j];
    mu2 *= 0.125f;
    float v2 = 0.f;
#pragma unroll
    for (int j = 0; j < 8; ++j) { const float d = pool[j] - mu2; v2 += d * d; }
    const float rs2 = rsqrtf(v2 * 0.125f + 1e-5f);
    float hh[8];
#pragma unroll
    for (int j = 0; j < 8; ++j) hh[j] = (pool[j] - mu2) * rs2 * cp_ln_g[j] + cp_ln_b[j];
    float r1[8];
#pragma unroll
    for (int j = 0; j < 8; ++j) {
        float a = cp_b1[j];
#pragma unroll
        for (int k = 0; k < 8; ++k) a += hh[k] * cp_w1[j * 8 + k];
        r1[j] = fmaxf(a, 0.f);
    }
    float cy[8];
#pragma unroll
    for (int j = 0; j < 8; ++j) {
        float a = cp_b2[j];
#pragma unroll
        for (int k = 0; k < 8; ++k) a += r1[k] * cp_w2[j * 8 + k];
        cy[j] = safef(a);
    }
    if (lane == 0) {
        *(float4*)(ws_cyc + nc * 8)     = make_float4(cy[0], cy[1], cy[2], cy[3]);
        *(float4*)(ws_cyc + nc * 8 + 4) = make_float4(cy[4], cy[5], cy[6], cy[7]);
    }

    // global-attention QKV row: lanes 0..23 each produce one output
    if (lane < 24) {
        const float* wrow = ia_in_w + lane * 8;
        float g2 = ia_in_b[lane];
#pragma unroll
        for (int k = 0; k < 8; ++k) g2 += cy[k] * wrow[k];
        if (lane < 8)       ws_q[nc * 8 + lane] = g2;
        else if (lane < 16) ws_kT[(lane - 8) * NCYC + nc] = g2;
        else                ws_vT[(lane - 16) * NCYC + nc] = g2;
    }
}

// ---------------------------------------------------------------------------
// Kernel 2: global attention (one wave per query, float4 K/V loads) fused
// with the final softmax-pool + MLP via the last-block pattern.
// ---------------------------------------------------------------------------
__global__ __launch_bounds__(256) void k_attn_final(
    const float* __restrict__ ws_cyc,
    const float* __restrict__ ws_q,
    const float* __restrict__ ws_kT,
    const float* __restrict__ ws_vT,
    const float* __restrict__ ia_out_w, const float* __restrict__ ia_out_b,
    const float* __restrict__ in_g, const float* __restrict__ in_b,
    const float* __restrict__ is_w, const float* __restrict__ is_b,
    const float* __restrict__ tp_ln_g, const float* __restrict__ tp_ln_b,
    const float* __restrict__ tp_w1, const float* __restrict__ tp_b1,
    const float* __restrict__ tp_w2, const float* __restrict__ tp_b2,
    float* __restrict__ ws_coll,  // [NCYC][8]
    float* __restrict__ ws_lg,    // [NCYC]
    unsigned* __restrict__ ws_cnt,
    float* __restrict__ out)
{
    __shared__ float sredM[4], sredS[4], spool[4][8];
    __shared__ unsigned s_last;

    const int lane = threadIdx.x & 63;
    const int wid  = threadIdx.x >> 6;
    const int g    = blockIdx.x * 4 + wid;

    float q[8];
#pragma unroll
    for (int d = 0; d < 8; ++d) q[d] = 0.5f * ws_q[g * 8 + d];   // fold 1/sqrt(4)

    // pass A: scores (4 tokens per j-step via float4), per-lane max
    float sc0[16], sc1[16];
    float m0 = -1e30f, m1 = -1e30f;
#pragma unroll
    for (int j = 0; j < 4; ++j) {
        const int t4 = j * 256 + lane * 4;
        float s0[4] = {0, 0, 0, 0}, s1[4] = {0, 0, 0, 0};
#pragma unroll
        for (int d = 0; d < 8; ++d) {
            const float4 kv = *(const float4*)(ws_kT + d * NCYC + t4);
            const float qd = q[d];
            float* s = (d < 4) ? s0 : s1;
            s[0] += qd * kv.x; s[1] += qd * kv.y; s[2] += qd * kv.z; s[3] += qd * kv.w;
        }
#pragma unroll
        for (int c = 0; c < 4; ++c) {
            sc0[j * 4 + c] = s0[c]; sc1[j * 4 + c] = s1[c];
            m0 = fmaxf(m0, s0[c]); m1 = fmaxf(m1, s1[c]);
        }
    }
    m0 = wmax_b(m0); m1 = wmax_b(m1);

    // pass B: exp + accumulate V
    float l0 = 0.f, l1 = 0.f;
    float a0[4] = {0, 0, 0, 0}, a1[4] = {0, 0, 0, 0};
#pragma unroll
    for (int j = 0; j < 4; ++j) {
        const int t4 = j * 256 + lane * 4;
        float e0[4], e1[4];
#pragma unroll
        for (int c = 0; c < 4; ++c) {
            e0[c] = __expf(sc0[j * 4 + c] - m0);
            e1[c] = __expf(sc1[j * 4 + c] - m1);
            l0 += e0[c]; l1 += e1[c];
        }
#pragma unroll
        for (int d = 0; d < 4; ++d) {
            const float4 v0 = *(const float4*)(ws_vT + d * NCYC + t4);
            const float4 v1 = *(const float4*)(ws_vT + (4 + d) * NCYC + t4);
            a0[d] += e0[0] * v0.x + e0[1] * v0.y + e0[2] * v0.z + e0[3] * v0.w;
            a1[d] += e1[0] * v1.x + e1[1] * v1.y + e1[2] * v1.z + e1[3] * v1.w;
        }
    }
    l0 = wsum_b(l0); l1 = wsum_b(l1);
#pragma unroll
    for (int d = 0; d < 4; ++d) { a0[d] = wsum_b(a0[d]); a1[d] = wsum_b(a1[d]); }

    float attn8[8];
#pragma unroll
    for (int d = 0; d < 4; ++d) { attn8[d] = a0[d] / l0; attn8[4 + d] = a1[d] / l1; }

    // epilogue (redundant across lanes; lane 0 stores)
    const float4 cyA = *(const float4*)(ws_cyc + g * 8);
    const float4 cyB = *(const float4*)(ws_cyc + g * 8 + 4);
    const float cyc[8] = {cyA.x, cyA.y, cyA.z, cyA.w, cyB.x, cyB.y, cyB.z, cyB.w};
    float x8[8];
#pragma unroll
    for (int j = 0; j < 8; ++j) {
        float ao = ia_out_b[j];
#pragma unroll
        for (int k = 0; k < 8; ++k) ao += attn8[k] * ia_out_w[j * 8 + k];
        x8[j] = safef(cyc[j] + ao);
    }
    float mu = 0.f;
#pragma unroll
    for (int j = 0; j < 8; ++j) mu += x8[j];
    mu *= 0.125f;
    float var = 0.f;
#pragma unroll
    for (int j = 0; j < 8; ++j) { const float d = x8[j] - mu; var += d * d; }
    var *= 0.125f;
    const float rs = rsqrtf(var + 1e-5f);
    float lgv = is_b[0];
    float cl8[8];
#pragma unroll
    for (int j = 0; j < 8; ++j) {
        cl8[j] = safef((x8[j] - mu) * rs * in_g[j] + in_b[j]);
        lgv += cl8[j] * is_w[j];
    }
    if (lane == 0) {
        *(float4*)(ws_coll + g * 8)     = make_float4(cl8[0], cl8[1], cl8[2], cl8[3]);
        *(float4*)(ws_coll + g * 8 + 4) = make_float4(cl8[4], cl8[5], cl8[6], cl8[7]);
        ws_lg[g] = safef(lgv);
    }

    // ---- last-block final: softmax-pool over 1024 tokens + MLP -> out[8] ----
    __syncthreads();
    if (threadIdx.x == 0) {
        __threadfence();
        const unsigned old = atomicAdd(ws_cnt, 1u);
        s_last = (old == NB2 - 1) ? 1u : 0u;
    }
    __syncthreads();
    if (!s_last) return;
    __threadfence();

    const int tid = threadIdx.x;
    float lgv4[4], cl[4][8];
#pragma unroll
    for (int r = 0; r < 4; ++r) {
        const int t = tid + 256 * r;
        lgv4[r] = ws_lg[t];
        const float4 u = *(const float4*)(ws_coll + t * 8);
        const float4 w = *(const float4*)(ws_coll + t * 8 + 4);
        cl[r][0] = u.x; cl[r][1] = u.y; cl[r][2] = u.z; cl[r][3] = u.w;
        cl[r][4] = w.x; cl[r][5] = w.y; cl[r][6] = w.z; cl[r][7] = w.w;
    }
    float m = fmaxf(fmaxf(lgv4[0], lgv4[1]), fmaxf(lgv4[2], lgv4[3]));
    m = wmax_b(m);
    if (lane == 0) sredM[wid] = m;
    __syncthreads();
    const float M = fmaxf(fmaxf(sredM[0], sredM[1]), fmaxf(sredM[2], sredM[3]));
    float er[4], es = 0.f;
#pragma unroll
    for (int r = 0; r < 4; ++r) { er[r] = __expf(lgv4[r] - M); es += er[r]; }
    es = wsum_b(es);
    if (lane == 0) sredS[wid] = es;
#pragma unroll
    for (int j = 0; j < 8; ++j) {
        float pj = er[0] * cl[0][j] + er[1] * cl[1][j] + er[2] * cl[2][j] + er[3] * cl[3][j];
        pj = wsum_b(pj);
        if (lane == 0) spool[wid][j] = pj;
    }
    __syncthreads();

    if (wid == 0) {
        const float S = sredS[0] + sredS[1] + sredS[2] + sredS[3];
        const float invS = 1.f / S;
        float pool[8];
#pragma unroll
        for (int j = 0; j < 8; ++j)
            pool[j] = (spool[0][j] + spool[1][j] + spool[2][j] + spool[3][j]) * invS;
        float mu2 = 0.f;
#pragma unroll
        for (int j = 0; j < 8; ++j) mu2 += pool[j];
        mu2 *= 0.125f;
        float v2 = 0.f;
#pragma unroll
        for (int j = 0; j < 8; ++j) { const float d = pool[j] - mu2; v2 += d * d; }
        const float rs2 = rsqrtf(v2 * 0.125f + 1e-5f);
        float hh[8];
#pragma unroll
        for (int j = 0; j < 8; ++j) hh[j] = (pool[j] - mu2) * rs2 * tp_ln_g[j] + tp_ln_b[j];
        float r1[8];
#pragma unroll
        for (int j = 0; j < 8; ++j) {
            float a = tp_b1[j];
#pragma unroll
            for (int k = 0; k < 8; ++k) a += hh[k] * tp_w1[j * 8 + k];
            r1[j] = fmaxf(a, 0.f);
        }
        if (lane == 0) {
#pragma unroll
            for (int j = 0; j < 8; ++j) {
                float a = tp_b2[j];
#pragma unroll
                for (int k = 0; k < 8; ++k) a += r1[k] * tp_w2[j * 8 + k];
                out[j] = safef(a);
            }
        }
    }
}

extern "C" void kernel_launch(void* const* d_in, const int* in_sizes, int n_in,
                              void* d_out, int out_size, void* d_ws, size_t ws_size,
                              hipStream_t stream) {
    const float* df       = (const float*)d_in[0];
    const float* de_w     = (const float*)d_in[1];
    const float* de_b     = (const float*)d_in[2];
    const float* ca_in_w  = (const float*)d_in[3];
    const float* ca_in_b  = (const float*)d_in[4];
    const float* ca_out_w = (const float*)d_in[5];
    const float* ca_out_b = (const float*)d_in[6];
    const float* cn_g     = (const float*)d_in[7];
    const float* cn_b     = (const float*)d_in[8];
    const float* cs_w     = (const float*)d_in[9];
    const float* cs_b     = (const float*)d_in[10];
    const float* cp_ln_g  = (const float*)d_in[11];
    const float* cp_ln_b  = (const float*)d_in[12];
    const float* cp_w1    = (const float*)d_in[13];
    const float* cp_b1    = (const float*)d_in[14];
    const float* cp_w2    = (const float*)d_in[15];
    const float* cp_b2    = (const float*)d_in[16];
    const float* ia_in_w  = (const float*)d_in[17];
    const float* ia_in_b  = (const float*)d_in[18];
    const float* ia_out_w = (const float*)d_in[19];
    const float* ia_out_b = (const float*)d_in[20];
    const float* in_g     = (const float*)d_in[21];
    const float* in_b     = (const float*)d_in[22];
    const float* is_w     = (const float*)d_in[23];
    const float* is_b     = (const float*)d_in[24];
    const float* tp_ln_g  = (const float*)d_in[25];
    const float* tp_ln_b  = (const float*)d_in[26];
    const float* tp_w1    = (const float*)d_in[27];
    const float* tp_b1    = (const float*)d_in[28];
    const float* tp_w2    = (const float*)d_in[29];
    const float* tp_b2    = (const float*)d_in[30];

    float* ws      = (float*)d_ws;
    float* ws_cyc  = ws;                    // 1024*8
    float* ws_q    = ws + NCYC * 8;         // 1024*8
    float* ws_kT   = ws + NCYC * 16;        // 8*1024 (transposed)
    float* ws_vT   = ws + NCYC * 24;        // 8*1024 (transposed)
    float* ws_coll = ws + NCYC * 32;        // 1024*8
    float* ws_lg   = ws + NCYC * 40;        // 1024
    unsigned* ws_cnt = (unsigned*)(ws + NCYC * 41);

    k_cycle<<<NCYC, 64, 0, stream>>>(
        df, de_w, de_b, ca_in_w, ca_in_b, ca_out_w, ca_out_b,
        cn_g, cn_b, cs_w, cs_b, cp_ln_g, cp_ln_b,
        cp_w1, cp_b1, cp_w2, cp_b2, ia_in_w, ia_in_b,
        ws_cyc, ws_q, ws_kT, ws_vT, ws_cnt);

    k_attn_final<<<NB2, 256, 0, stream>>>(
        ws_cyc, ws_q, ws_kT, ws_vT, ia_out_w, ia_out_b, in_g, in_b, is_w, is_b,
        tp_ln_g, tp_ln_b, tp_w1, tp_b1, tp_w2, tp_b2,
        ws_coll, ws_lg, ws_cnt, (float*)d_out);
}